// Round 10
// baseline (184.534 us; speedup 1.0000x reference)
//
#include <hip/hip_runtime.h>

typedef unsigned short u16;
typedef unsigned int u32;
typedef __bf16 bf16x8 __attribute__((ext_vector_type(8)));
typedef float f32x4 __attribute__((ext_vector_type(4)));

#define EMB 768
#define NH 12
#define HD 64
#define SEQ 512
#define NB 8
#define NLROWS 4096   // N*L
#define PEROWS 1024   // padded; row 1023 duplicates 1022 (only feeds unused MFMA lanes)

__device__ __forceinline__ float b2f(u16 u) {
    return __uint_as_float(((u32)u) << 16);
}
__device__ __forceinline__ u16 f2b(float f) {
    u32 x = __float_as_uint(f);
    u32 r = x + 0x7fffu + ((x >> 16) & 1u);
    return (u16)(r >> 16);
}
__device__ __forceinline__ u32 pack2(float a, float b) {
    return (u32)f2b(a) | ((u32)f2b(b) << 16);
}
// packed f32->bf16 (RNE), 1 VALU op instead of 6 — used only in attn hot loop
__device__ __forceinline__ u32 cvtpk(float lo, float hi) {
    u32 r;
    asm("v_cvt_pk_bf16_f32 %0, %1, %2" : "=v"(r) : "v"(lo), "v"(hi));
    return r;
}
// compiler-level memory fence: forbids cross-phase reordering of the type-punned
// psd LDS accesses (uint2 stores vs u16/bf16x8 loads -> TBAA would allow it).
__device__ __forceinline__ void cfence() { asm volatile("" ::: "memory"); }
// async global->LDS, 16B per lane; LDS dest = wave-uniform base + lane*16
__device__ __forceinline__ void gl_lds16(const u16* g, u16* l) {
    __builtin_amdgcn_global_load_lds((const __attribute__((address_space(1))) u32*)g,
                                     (__attribute__((address_space(3))) u32*)l, 16, 0, 0);
}

// ---------------------------------------------------------------- prep: transpose5 + pe + cvt3 in one launch
__global__ __launch_bounds__(256) void prep(
        const float* __restrict__ Wq, const float* __restrict__ Wk, const float* __restrict__ Wv,
        const float* __restrict__ Wo, const float* __restrict__ Wpos,
        u16* __restrict__ Wt, u16* __restrict__ pe,
        const float* __restrict__ q, const float* __restrict__ k, const float* __restrict__ v,
        u16* __restrict__ qc, u16* __restrict__ kc, u16* __restrict__ vc) {
    __shared__ u16 tile[32][33];
    int b = blockIdx.x;
    int tid = threadIdx.x;
    if (b < 2880) {
        // transpose+bf16ify the 5 weight matrices
        int m = b / 576, r = b % 576;
        const float* src = (m == 0) ? Wq : (m == 1) ? Wk : (m == 2) ? Wv : (m == 3) ? Wo : Wpos;
        u16* dst = Wt + (size_t)m * EMB * EMB;
        int bx = (r % 24) * 32, by = (r / 24) * 32;
        int tx = tid & 31, ty = tid >> 5;
#pragma unroll
        for (int i = 0; i < 32; i += 8)
            tile[ty + i][tx] = f2b(src[(size_t)(by + ty + i) * EMB + bx + tx]);
        __syncthreads();
        // write side: 2 consecutive out-cols per lane -> u32 stores (2x wider than scalar u16)
        int c2 = (tid & 15) * 2, rw = tid >> 4;
#pragma unroll
        for (int i = 0; i < 32; i += 16) {
            int row = rw + i;
            u32 val = (u32)tile[c2][row] | ((u32)tile[c2 + 1][row] << 16);
            *(u32*)&dst[(size_t)(bx + row) * EMB + by + c2] = val;
        }
    } else if (b < 3904) {
        // sinusoid table rows 0..1023 (1023 dup of 1022)
        int pos = b - 2880;
        int p2 = pos > 1022 ? 1022 : pos;
#pragma unroll
        for (int j = 0; j < 3; j++) {
            int col = tid + j * 256;
            int i = col >> 1;
            float ang = (float)p2 * __expf(-0.023985261384f * (float)i);
            float val = (col & 1) ? __cosf(ang) : __sinf(ang);
            pe[(size_t)pos * EMB + col] = f2b(val);
        }
    } else {
        // fp32 -> bf16 bulk convert q,k,v
        int idx = b - 3904;              // [0, 4608)
        int w = idx / 1536, bx = idx % 1536;
        const float* s = (w == 0) ? q : (w == 1) ? k : v;
        u16* d = (w == 0) ? qc : (w == 1) ? kc : vc;
        size_t i = ((size_t)bx * 256 + tid) * 8;
        float4 f0 = *(const float4*)(s + i);
        float4 f1 = *(const float4*)(s + i + 4);
        uint4 o;
        o.x = pack2(f0.x, f0.y); o.y = pack2(f0.z, f0.w);
        o.z = pack2(f1.x, f1.y); o.w = pack2(f1.z, f1.w);
        *(uint4*)(d + i) = o;
    }
}

// ---------------------------------------------------------------- C[M,768] = A[M,768] @ Bt^T + bias
// BM x BN tile, BK=64, XOR-swizzled unpadded LDS, global_load_lds staging.
// NZ=4: z selects (A,W,bias,C); z==2 writes V^T layout; z==3 is the 1024-row R GEMM.
// launch_bounds (256,3): 128x128 instance needs ~115 VGPR (acc[4][4]=64) — the 4-wave
// 128-VGPR cap would spill; grids are 3 blocks/CU anyway.
template <int BM, int BN, int NZ, bool OUTF32>
__global__ __launch_bounds__(256, 3) void gemm_k(
        const u16* A0, const u16* A1, const u16* A2, const u16* A3,
        const u16* W0, const u16* W1, const u16* W2, const u16* W3,
        const float* f0, const float* f1, const float* f2, const float* f3,
        void* C0, void* C1, void* C2, void* C3) {
    constexpr int RT = BM / 32;          // row tiles of 16 per wave
    constexpr int CT = BN / 32;          // col tiles of 16 per wave
    __shared__ __align__(16) u16 As[BM * 64];
    __shared__ __align__(16) u16 Bs[BN * 64];
    int z = (NZ > 1) ? blockIdx.z : 0;
    if (NZ > 1 && z == 3 && blockIdx.x >= PEROWS / BM) return;
    const u16* A = (z == 0) ? A0 : (z == 1) ? A1 : (z == 2) ? A2 : A3;
    const u16* Bt = (z == 0) ? W0 : (z == 1) ? W1 : (z == 2) ? W2 : W3;
    const float* bias = (z == 0) ? f0 : (z == 1) ? f1 : (z == 2) ? f2 : f3;
    void* Cv = (z == 0) ? C0 : (z == 1) ? C1 : (z == 2) ? C2 : C3;
    bool vtout = (NZ > 1) && (z == 2);

    int tid = threadIdx.x;
    int wave = tid >> 6, lane = tid & 63;
    int lrow = lane & 15, lq = lane >> 4;
    int lr8 = lane >> 3, lb = lane & 7;
    int m0 = blockIdx.x * BM, n0 = blockIdx.y * BN;
    int wr = (wave >> 1) * (BM / 2), wc = (wave & 1) * (BN / 2);
    const u16* Abase = A + (size_t)m0 * EMB + (size_t)(lb ^ lr8) * 8;
    const u16* Bbase = Bt + (size_t)n0 * EMB + (size_t)(lb ^ lr8) * 8;
    f32x4 acc[RT][CT] = {};

    for (int k0 = 0; k0 < EMB; k0 += 64) {
        __syncthreads();
#pragma unroll
        for (int j = 0; j < BM / 32; j++) {
            int row = j * 32 + wave * 8 + lr8;
            gl_lds16(Abase + (size_t)row * EMB + k0, &As[(j * 32 + wave * 8) * 64]);
        }
#pragma unroll
        for (int j = 0; j < BN / 32; j++) {
            int row = j * 32 + wave * 8 + lr8;
            gl_lds16(Bbase + (size_t)row * EMB + k0, &Bs[(j * 32 + wave * 8) * 64]);
        }
        __syncthreads();
#pragma unroll
        for (int ks = 0; ks < 2; ks++) {
            int pb = (ks * 4 + lq) ^ (lrow & 7);
            bf16x8 bfr[CT];
#pragma unroll
            for (int ct = 0; ct < CT; ct++)
                bfr[ct] = *(const bf16x8*)&Bs[(wc + ct * 16 + lrow) * 64 + pb * 8];
#pragma unroll
            for (int rt = 0; rt < RT; rt++) {
                bf16x8 afr = *(const bf16x8*)&As[(wr + rt * 16 + lrow) * 64 + pb * 8];
#pragma unroll
                for (int ct = 0; ct < CT; ct++)
                    acc[rt][ct] = __builtin_amdgcn_mfma_f32_16x16x32_bf16(afr, bfr[ct], acc[rt][ct], 0, 0, 0);
            }
        }
    }
#pragma unroll
    for (int rt = 0; rt < RT; rt++) {
#pragma unroll
        for (int ct = 0; ct < CT; ct++) {
            int col = n0 + wc + ct * 16 + lrow;
            float bvv = bias[col];
            int mrow = m0 + wr + rt * 16 + lq * 4;
            if (vtout) {
                // V^T per (n,h): Vtg[((n*12+h)*64 + d)*512 + kv], 4 kv packed
                int nb = mrow >> 9, kvl = mrow & 511;
                int hh = col >> 6, dl = col & 63;
                ushort4 pk;
                pk.x = f2b(acc[rt][ct][0] + bvv);
                pk.y = f2b(acc[rt][ct][1] + bvv);
                pk.z = f2b(acc[rt][ct][2] + bvv);
                pk.w = f2b(acc[rt][ct][3] + bvv);
                *(ushort4*)((u16*)Cv + (((size_t)(nb * NH + hh) * HD + dl) << 9) + kvl) = pk;
            } else if (OUTF32) {
#pragma unroll
                for (int r = 0; r < 4; r++)
                    ((float*)Cv)[(size_t)(mrow + r) * EMB + col] = acc[rt][ct][r] + bvv;
            } else {
#pragma unroll
                for (int r = 0; r < 4; r++)
                    ((u16*)Cv)[(size_t)(mrow + r) * EMB + col] = f2b(acc[rt][ct][r] + bvv);
            }
        }
    }
}

// ---------------------------------------------------------------- fused attention (R16 = R15 + V-direct)
// V fragments now read STRAIGHT from global (Vt LDS tile deleted): unlike R11's R-direct
// failure (consumed in-phase -> latency exposed), vf is consumed only in the PV phase
// after the whole softmax -> L2 latency hides under it. Access is dense (chunk reads
// 128B contiguous per V^T row) and L2-served (8 q-tile blocks share the panel).
// Per wave-chunk: ds_read_b128 26 -> 18, staging DMA 8 -> 6 groups, LDS 45.6 -> 37.6 KB.
// Swizzle identity (verified): LDS[r][c8] = V^T[r][c8^(r&7)], pb read cancels -> logical
// col8 = ks*4+lq; direct addr = Vtg[((n*12+h)*64+dt*16+lrow)*512 + c0 + ks*32 + lq*8].
// cfences kept (psd TBAA hazard). No setprio (R14: +1.5us). No circular-R (R13: -2.6us).
// Wave w owns q rows [w*16, w*16+16). QK^T operand-swapped (lane: k=lq*4+r, q=lrow).
__global__ __launch_bounds__(256, 3) void attn_rpe(
        const u16* __restrict__ Qb, const u16* __restrict__ Kb, const u16* __restrict__ Vtg,
        const u16* __restrict__ Rb, const float* __restrict__ rwb, const float* __restrict__ rrb,
        u16* __restrict__ Ctx) {
    __shared__ __align__(16) u16 Ks[64 * 64];
    __shared__ __align__(16) u16 Rs[128 * 64];
    // per-wave region (1664 u16 = 3328 B): Psd[80][20] (1600), later reused as Pb[16][72] (1152)
    __shared__ __align__(16) u16 PsPb[4 * 1664];

    int q0 = blockIdx.x * 64;
    int h = blockIdx.y;
    int n = blockIdx.z;
    int tid = threadIdx.x;
    int wave = tid >> 6, lane = tid & 63;
    int lrow = lane & 15, lq = lane >> 4;
    int lr8 = lane >> 3, lb = lane & 7;
    int swz = (lb ^ lr8) * 8;
    u16* psd = &PsPb[wave * 1664];
    // per-lane V^T base: row lrow (d-offset added per dt), col lq*8
    const u16* vrow = Vtg + (((size_t)(n * NH + h) * HD + lrow) << 9) + lq * 8;

    // ---- Q fragments straight from global: aw = Q+rwb, ar = Q+rrb (bf16)
    bf16x8 aw[2], ar[2];
    {
        const u16* qrow = Qb + ((size_t)(n * SEQ + q0 + wave * 16 + lrow)) * EMB + h * HD;
#pragma unroll
        for (int ks = 0; ks < 2; ks++) {
            int c = ks * 32 + lq * 8;
            uint4 qv = *(const uint4*)(qrow + c);
            float4 w0 = *(const float4*)(rwb + h * HD + c);
            float4 w1 = *(const float4*)(rwb + h * HD + c + 4);
            float4 r0 = *(const float4*)(rrb + h * HD + c);
            float4 r1 = *(const float4*)(rrb + h * HD + c + 4);
            union { uint4 u; u16 s[8]; } qu; qu.u = qv;
            union { uint4 u; bf16x8 v; } ww, rr;
            ww.u.x = pack2(b2f(qu.s[0]) + w0.x, b2f(qu.s[1]) + w0.y);
            ww.u.y = pack2(b2f(qu.s[2]) + w0.z, b2f(qu.s[3]) + w0.w);
            ww.u.z = pack2(b2f(qu.s[4]) + w1.x, b2f(qu.s[5]) + w1.y);
            ww.u.w = pack2(b2f(qu.s[6]) + w1.z, b2f(qu.s[7]) + w1.w);
            rr.u.x = pack2(b2f(qu.s[0]) + r0.x, b2f(qu.s[1]) + r0.y);
            rr.u.y = pack2(b2f(qu.s[2]) + r0.z, b2f(qu.s[3]) + r0.w);
            rr.u.z = pack2(b2f(qu.s[4]) + r1.x, b2f(qu.s[5]) + r1.y);
            rr.u.w = pack2(b2f(qu.s[6]) + r1.z, b2f(qu.s[7]) + r1.w);
            aw[ks] = ww.v;
            ar[ks] = rr.v;
        }
    }

    auto stage_chunk = [&](int cc) {
#pragma unroll
        for (int j = 0; j < 2; j++) {      // K tile [kv][d]
            int row = j * 32 + wave * 8 + lr8;
            gl_lds16(Kb + ((size_t)(n * SEQ + cc + row)) * EMB + h * HD + swz,
                     &Ks[(j * 32 + wave * 8) * 64]);
        }
#pragma unroll
        for (int j = 0; j < 4; j++) {      // R band rows t0..t0+127, t0 = q0-cc+448 in [0,1023]
            int row = j * 32 + wave * 8 + lr8;
            gl_lds16(Rb + (size_t)(q0 - cc + 448 + row) * EMB + h * HD + swz,
                     &Rs[(j * 32 + wave * 8) * 64]);
        }
    };

    float lsum = 0.f;
    f32x4 acco[4] = {};

    stage_chunk(0);
    for (int c0 = 0; c0 < SEQ; c0 += 64) {
        __syncthreads();  // staging complete (vmcnt drained at barrier); prior LDS reads done

        // V fragments direct from global (consumed in PV, after softmax -> latency hidden)
        bf16x8 vf[2][4];
#pragma unroll
        for (int ks = 0; ks < 2; ks++)
#pragma unroll
            for (int dt = 0; dt < 4; dt++)
                vf[ks][dt] = *(const bf16x8*)(vrow + ((size_t)(dt * 16) << 9) + c0 + ks * 32);

        f32x4 sacc[4] = {};
        f32x4 pacc[5] = {};
#pragma unroll
        for (int ks = 0; ks < 2; ks++) {
            int pb = (ks * 4 + lq) ^ (lrow & 7);
#pragma unroll
            for (int ct = 0; ct < 4; ct++) {
                bf16x8 bk = *(const bf16x8*)&Ks[(ct * 16 + lrow) * 64 + pb * 8];
                // swapped: A = K-tile rows (kv), B = Q rows -> D[kv][q]
                sacc[ct] = __builtin_amdgcn_mfma_f32_16x16x32_bf16(bk, aw[ks], sacc[ct], 0, 0, 0);
            }
#pragma unroll
            for (int jj = 0; jj < 5; jj++) {
                bf16x8 br = *(const bf16x8*)&Rs[((wave + jj) * 16 + lrow) * 64 + pb * 8];
                pacc[jj] = __builtin_amdgcn_mfma_f32_16x16x32_bf16(ar[ks], br, pacc[jj], 0, 0, 0);
            }
        }
        __syncthreads();  // all waves done reading Ks/Rs
        if (c0 + 64 < SEQ) stage_chunk(c0 + 64);  // overlaps the softmax/PV phase below

        // scatter banded P transposed: Psd[jwin][qlocal], one b64 per jj (wave-private region)
#pragma unroll
        for (int jj = 0; jj < 5; jj++) {
            uint2 pk2;
            pk2.x = cvtpk(pacc[jj][0], pacc[jj][1]);
            pk2.y = cvtpk(pacc[jj][2], pacc[jj][3]);
            *(uint2*)&psd[(jj * 16 + lrow) * 20 + lq * 4] = pk2;
        }
        cfence();  // scatter stores must complete (program order) before gather loads

        // gather bd for the SWAPPED layout: this lane owns (k = ct*16+lq*4+r, q = lrow)
        float bd[4][4];
#pragma unroll
        for (int ct = 0; ct < 4; ct++)
#pragma unroll
            for (int r = 0; r < 4; r++) {
                int jwin = lrow - (ct * 16 + lq * 4 + r) + 63;  // in [0,78]
                bd[ct][r] = b2f(psd[jwin * 20 + lrow]);
            }
        cfence();  // all gathers read before Pb stores overwrite the region

        // p = 2^((ac+bd)*0.125/ln2) (no max subtraction), per-lane row partial (q=lrow),
        // vectorized store Pb[qlocal][k]: lane's 4 k are consecutive -> one b64 per ct
#pragma unroll
        for (int ct = 0; ct < 4; ct++) {
            float p0 = exp2f((sacc[ct][0] + bd[ct][0]) * 0.18033688011f);
            float p1 = exp2f((sacc[ct][1] + bd[ct][1]) * 0.18033688011f);
            float p2 = exp2f((sacc[ct][2] + bd[ct][2]) * 0.18033688011f);
            float p3 = exp2f((sacc[ct][3] + bd[ct][3]) * 0.18033688011f);
            lsum += (p0 + p1) + (p2 + p3);
            uint2 pk2;
            pk2.x = cvtpk(p0, p1);
            pk2.y = cvtpk(p2, p3);
            *(uint2*)&psd[lrow * 72 + ct * 16 + lq * 4] = pk2;
        }
        cfence();  // Pb stores complete before PV fragment loads

        // PV operand-swapped: A = V-frag (d rows), B = P-frag (q rows) -> acco[dt] = O[d][q]
#pragma unroll
        for (int ks = 0; ks < 2; ks++) {
            bf16x8 pf = *(const bf16x8*)&psd[lrow * 72 + ks * 32 + lq * 8];
#pragma unroll
            for (int dt = 0; dt < 4; dt++)
                acco[dt] = __builtin_amdgcn_mfma_f32_16x16x32_bf16(vf[ks][dt], pf, acco[dt], 0, 0, 0);
        }
    }

    // epilogue: lane's partial is for q = lrow; reduce across the 4 lq-groups, no LDS needed
    lsum += __shfl_xor(lsum, 16);
    lsum += __shfl_xor(lsum, 32);
    float inv = 1.0f / lsum;
    int q = q0 + wave * 16 + lrow;
#pragma unroll
    for (int dt = 0; dt < 4; dt++) {
        ushort4 pk;
        pk.x = f2b(acco[dt][0] * inv);
        pk.y = f2b(acco[dt][1] * inv);
        pk.z = f2b(acco[dt][2] * inv);
        pk.w = f2b(acco[dt][3] * inv);
        *(ushort4*)&Ctx[((size_t)(n * SEQ + q)) * EMB + h * HD + dt * 16 + lq * 4] = pk;
    }
}

// ----------------------------------------------------------------
extern "C" void kernel_launch(void* const* d_in, const int* in_sizes, int n_in,
                              void* d_out, int out_size, void* d_ws, size_t ws_size,
                              hipStream_t stream) {
    const float* values = (const float*)d_in[0];
    const float* keys   = (const float*)d_in[1];
    const float* query  = (const float*)d_in[2];
    const float* Wq = (const float*)d_in[3];
    const float* bq = (const float*)d_in[4];
    const float* Wk = (const float*)d_in[5];
    const float* bk = (const float*)d_in[6];
    const float* Wv = (const float*)d_in[7];
    const float* bv = (const float*)d_in[8];
    const float* Wo = (const float*)d_in[9];
    const float* bo = (const float*)d_in[10];
    const float* Wpos = (const float*)d_in[11];
    const float* bpos = (const float*)d_in[12];
    const float* rwb = (const float*)d_in[13];
    const float* rrb = (const float*)d_in[14];
    float* out = (float*)d_out;

    u16* ws = (u16*)d_ws;
    size_t off = 0;
    u16* Wt = ws;            off += (size_t)5 * EMB * EMB;   // Wq^T,Wk^T,Wv^T,Wo^T,Wpos^T (bf16)
    u16* pe = ws + off;      off += (size_t)PEROWS * EMB;
    u16* Rb = ws + off;      off += (size_t)PEROWS * EMB;
    u16* qc = ws + off;      off += (size_t)NLROWS * EMB;    // bf16 query
    u16* kc = ws + off;      off += (size_t)NLROWS * EMB;    // bf16 keys
    u16* vc = ws + off;      off += (size_t)NLROWS * EMB;    // bf16 values
    u16* Qp = ws + off;      off += (size_t)NLROWS * EMB;    // Q projection
    u16* Kp = ws + off;      off += (size_t)NLROWS * EMB;    // K projection
    u16* Vtg = ws + off;     off += (size_t)NLROWS * EMB;    // V^T per (n,h): [n][h][d][kv]
    u16* Cx = qc;            // attention output (qc dead after fused GEMM dispatch)

    prep<<<dim3(8512), dim3(256), 0, stream>>>(Wq, Wk, Wv, Wo, Wpos, Wt, pe,
                                               query, keys, values, qc, kc, vc);

    // fused Q/K/V/R projection GEMMs: z = 0:Q 1:K 2:V(->V^T) 3:R(pe@Wpos, 1024 rows)
    // 128x128 tile: MFMA:DS 32:16 per wave-iter, grid (32,6,4) = 768 blocks = 3/CU.
    gemm_k<128, 128, 4, false><<<dim3(32, 6, 4), dim3(256), 0, stream>>>(
        qc, kc, vc, pe,
        Wt, Wt + (size_t)1 * EMB * EMB, Wt + (size_t)2 * EMB * EMB, Wt + (size_t)4 * EMB * EMB,
        bq, bk, bv, bpos,
        Qp, Kp, Vtg, Rb);

    attn_rpe<<<dim3(8, NH, NB), dim3(256), 0, stream>>>(Qp, Kp, Vtg, Rb, rwb, rrb, Cx);

    // output GEMM: 64x64 tiles -> 768 blocks = 3 blocks/CU (R12: beat 64x96's 2/CU).
    gemm_k<64, 64, 1, true><<<dim3(64, 12), dim3(256), 0, stream>>>(
        Cx, Cx, Cx, Cx,
        Wt + (size_t)3 * EMB * EMB, Wt + (size_t)3 * EMB * EMB,
        Wt + (size_t)3 * EMB * EMB, Wt + (size_t)3 * EMB * EMB,
        bo, bo, bo, bo,
        out, out, out, out);
}

// Round 11
// 173.440 us; speedup vs baseline: 1.0640x; 1.0640x over previous
//
#include <hip/hip_runtime.h>

typedef unsigned short u16;
typedef unsigned int u32;
typedef __bf16 bf16x8 __attribute__((ext_vector_type(8)));
typedef float f32x4 __attribute__((ext_vector_type(4)));

#define EMB 768
#define NH 12
#define HD 64
#define SEQ 512
#define NB 8
#define NLROWS 4096   // N*L
#define PEROWS 1024   // padded; row 1023 duplicates 1022 (only feeds unused MFMA lanes)

__device__ __forceinline__ float b2f(u16 u) {
    return __uint_as_float(((u32)u) << 16);
}
__device__ __forceinline__ u16 f2b(float f) {
    u32 x = __float_as_uint(f);
    u32 r = x + 0x7fffu + ((x >> 16) & 1u);
    return (u16)(r >> 16);
}
__device__ __forceinline__ u32 pack2(float a, float b) {
    return (u32)f2b(a) | ((u32)f2b(b) << 16);
}
// packed f32->bf16 (RNE), 1 VALU op instead of 6 — used only in attn hot loop
__device__ __forceinline__ u32 cvtpk(float lo, float hi) {
    u32 r;
    asm("v_cvt_pk_bf16_f32 %0, %1, %2" : "=v"(r) : "v"(lo), "v"(hi));
    return r;
}
// compiler-level memory fence: forbids cross-phase reordering of the type-punned
// psd LDS accesses (uint2 stores vs u16/bf16x8 loads -> TBAA would allow it).
__device__ __forceinline__ void cfence() { asm volatile("" ::: "memory"); }
// async global->LDS, 16B per lane; LDS dest = wave-uniform base + lane*16
__device__ __forceinline__ void gl_lds16(const u16* g, u16* l) {
    __builtin_amdgcn_global_load_lds((const __attribute__((address_space(1))) u32*)g,
                                     (__attribute__((address_space(3))) u32*)l, 16, 0, 0);
}

// ---------------------------------------------------------------- prep: transpose5 + pe + cvt3 in one launch
__global__ __launch_bounds__(256) void prep(
        const float* __restrict__ Wq, const float* __restrict__ Wk, const float* __restrict__ Wv,
        const float* __restrict__ Wo, const float* __restrict__ Wpos,
        u16* __restrict__ Wt, u16* __restrict__ pe,
        const float* __restrict__ q, const float* __restrict__ k, const float* __restrict__ v,
        u16* __restrict__ qc, u16* __restrict__ kc, u16* __restrict__ vc) {
    __shared__ u16 tile[32][33];
    int b = blockIdx.x;
    int tid = threadIdx.x;
    if (b < 2880) {
        // transpose+bf16ify the 5 weight matrices
        int m = b / 576, r = b % 576;
        const float* src = (m == 0) ? Wq : (m == 1) ? Wk : (m == 2) ? Wv : (m == 3) ? Wo : Wpos;
        u16* dst = Wt + (size_t)m * EMB * EMB;
        int bx = (r % 24) * 32, by = (r / 24) * 32;
        int tx = tid & 31, ty = tid >> 5;
#pragma unroll
        for (int i = 0; i < 32; i += 8)
            tile[ty + i][tx] = f2b(src[(size_t)(by + ty + i) * EMB + bx + tx]);
        __syncthreads();
        // write side: 2 consecutive out-cols per lane -> u32 stores (2x wider than scalar u16)
        int c2 = (tid & 15) * 2, rw = tid >> 4;
#pragma unroll
        for (int i = 0; i < 32; i += 16) {
            int row = rw + i;
            u32 val = (u32)tile[c2][row] | ((u32)tile[c2 + 1][row] << 16);
            *(u32*)&dst[(size_t)(bx + row) * EMB + by + c2] = val;
        }
    } else if (b < 3904) {
        // sinusoid table rows 0..1023 (1023 dup of 1022)
        int pos = b - 2880;
        int p2 = pos > 1022 ? 1022 : pos;
#pragma unroll
        for (int j = 0; j < 3; j++) {
            int col = tid + j * 256;
            int i = col >> 1;
            float ang = (float)p2 * __expf(-0.023985261384f * (float)i);
            float val = (col & 1) ? __cosf(ang) : __sinf(ang);
            pe[(size_t)pos * EMB + col] = f2b(val);
        }
    } else {
        // fp32 -> bf16 bulk convert q,k,v
        int idx = b - 3904;              // [0, 4608)
        int w = idx / 1536, bx = idx % 1536;
        const float* s = (w == 0) ? q : (w == 1) ? k : v;
        u16* d = (w == 0) ? qc : (w == 1) ? kc : vc;
        size_t i = ((size_t)bx * 256 + tid) * 8;
        float4 f0 = *(const float4*)(s + i);
        float4 f1 = *(const float4*)(s + i + 4);
        uint4 o;
        o.x = pack2(f0.x, f0.y); o.y = pack2(f0.z, f0.w);
        o.z = pack2(f1.x, f1.y); o.w = pack2(f1.z, f1.w);
        *(uint4*)(d + i) = o;
    }
}

// ---------------------------------------------------------------- C[M,768] = A[M,768] @ Bt^T + bias
// BM x BN tile, BK=64, XOR-swizzled unpadded LDS, global_load_lds staging.
// NZ=4: z selects (A,W,bias,C); z==2 writes V^T layout; z==3 is the 1024-row R GEMM.
// launch_bounds (256,3): 128x128 instance needs ~115 VGPR (acc[4][4]=64) — the 4-wave
// 128-VGPR cap would spill; grids are 3 blocks/CU anyway.
template <int BM, int BN, int NZ, bool OUTF32>
__global__ __launch_bounds__(256, 3) void gemm_k(
        const u16* A0, const u16* A1, const u16* A2, const u16* A3,
        const u16* W0, const u16* W1, const u16* W2, const u16* W3,
        const float* f0, const float* f1, const float* f2, const float* f3,
        void* C0, void* C1, void* C2, void* C3) {
    constexpr int RT = BM / 32;          // row tiles of 16 per wave
    constexpr int CT = BN / 32;          // col tiles of 16 per wave
    __shared__ __align__(16) u16 As[BM * 64];
    __shared__ __align__(16) u16 Bs[BN * 64];
    int z = (NZ > 1) ? blockIdx.z : 0;
    if (NZ > 1 && z == 3 && blockIdx.x >= PEROWS / BM) return;
    const u16* A = (z == 0) ? A0 : (z == 1) ? A1 : (z == 2) ? A2 : A3;
    const u16* Bt = (z == 0) ? W0 : (z == 1) ? W1 : (z == 2) ? W2 : W3;
    const float* bias = (z == 0) ? f0 : (z == 1) ? f1 : (z == 2) ? f2 : f3;
    void* Cv = (z == 0) ? C0 : (z == 1) ? C1 : (z == 2) ? C2 : C3;
    bool vtout = (NZ > 1) && (z == 2);

    int tid = threadIdx.x;
    int wave = tid >> 6, lane = tid & 63;
    int lrow = lane & 15, lq = lane >> 4;
    int lr8 = lane >> 3, lb = lane & 7;
    int m0 = blockIdx.x * BM, n0 = blockIdx.y * BN;
    int wr = (wave >> 1) * (BM / 2), wc = (wave & 1) * (BN / 2);
    const u16* Abase = A + (size_t)m0 * EMB + (size_t)(lb ^ lr8) * 8;
    const u16* Bbase = Bt + (size_t)n0 * EMB + (size_t)(lb ^ lr8) * 8;
    f32x4 acc[RT][CT] = {};

    for (int k0 = 0; k0 < EMB; k0 += 64) {
        __syncthreads();
#pragma unroll
        for (int j = 0; j < BM / 32; j++) {
            int row = j * 32 + wave * 8 + lr8;
            gl_lds16(Abase + (size_t)row * EMB + k0, &As[(j * 32 + wave * 8) * 64]);
        }
#pragma unroll
        for (int j = 0; j < BN / 32; j++) {
            int row = j * 32 + wave * 8 + lr8;
            gl_lds16(Bbase + (size_t)row * EMB + k0, &Bs[(j * 32 + wave * 8) * 64]);
        }
        __syncthreads();
#pragma unroll
        for (int ks = 0; ks < 2; ks++) {
            int pb = (ks * 4 + lq) ^ (lrow & 7);
            bf16x8 bfr[CT];
#pragma unroll
            for (int ct = 0; ct < CT; ct++)
                bfr[ct] = *(const bf16x8*)&Bs[(wc + ct * 16 + lrow) * 64 + pb * 8];
#pragma unroll
            for (int rt = 0; rt < RT; rt++) {
                bf16x8 afr = *(const bf16x8*)&As[(wr + rt * 16 + lrow) * 64 + pb * 8];
#pragma unroll
                for (int ct = 0; ct < CT; ct++)
                    acc[rt][ct] = __builtin_amdgcn_mfma_f32_16x16x32_bf16(afr, bfr[ct], acc[rt][ct], 0, 0, 0);
            }
        }
    }
#pragma unroll
    for (int rt = 0; rt < RT; rt++) {
#pragma unroll
        for (int ct = 0; ct < CT; ct++) {
            int col = n0 + wc + ct * 16 + lrow;
            float bvv = bias[col];
            int mrow = m0 + wr + rt * 16 + lq * 4;
            if (vtout) {
                // V^T per (n,h): Vtg[((n*12+h)*64 + d)*512 + kv], 4 kv packed
                int nb = mrow >> 9, kvl = mrow & 511;
                int hh = col >> 6, dl = col & 63;
                ushort4 pk;
                pk.x = f2b(acc[rt][ct][0] + bvv);
                pk.y = f2b(acc[rt][ct][1] + bvv);
                pk.z = f2b(acc[rt][ct][2] + bvv);
                pk.w = f2b(acc[rt][ct][3] + bvv);
                *(ushort4*)((u16*)Cv + (((size_t)(nb * NH + hh) * HD + dl) << 9) + kvl) = pk;
            } else if (OUTF32) {
#pragma unroll
                for (int r = 0; r < 4; r++)
                    ((float*)Cv)[(size_t)(mrow + r) * EMB + col] = acc[rt][ct][r] + bvv;
            } else {
#pragma unroll
                for (int r = 0; r < 4; r++)
                    ((u16*)Cv)[(size_t)(mrow + r) * EMB + col] = f2b(acc[rt][ct][r] + bvv);
            }
        }
    }
}

// ---------------------------------------------------------------- fused attention (R17 = R15 exactly, the 173.5us optimum)
// Structure lesson (R11/R13/R16, three-way confirmed): hipcc drains vmcnt(0) at every
// s_barrier, so in this 2-barrier loop ONLY global_load_lds staging is latency-free
// (drains while waves compute the previous chunk); any direct global load or extra
// VALU inside the barrier-to-barrier phases is fully exposed. Hence: staged Ks/Vt/Rs,
// offset-folded ds_reads, no setprio (R14: +1.5us), no circular-R (R13: -2.6us),
// no V/R-direct (R16/R11: -11us each), original dispatch grid (R10: remap -3us).
// cfences pin the psd type-punning order hazard (R8/R9 failures).
// Wave w owns q rows [w*16, w*16+16). QK^T operand-swapped (lane: k=lq*4+r, q=lrow).
__global__ __launch_bounds__(256, 3) void attn_rpe(
        const u16* __restrict__ Qb, const u16* __restrict__ Kb, const u16* __restrict__ Vtg,
        const u16* __restrict__ Rb, const float* __restrict__ rwb, const float* __restrict__ rrb,
        u16* __restrict__ Ctx) {
    __shared__ __align__(16) u16 Ks[64 * 64];
    __shared__ __align__(16) u16 Vt[64 * 64];
    __shared__ __align__(16) u16 Rs[128 * 64];
    // per-wave region (1664 u16 = 3328 B): Psd[80][20] (1600), later reused as Pb[16][72] (1152)
    __shared__ __align__(16) u16 PsPb[4 * 1664];

    int q0 = blockIdx.x * 64;
    int h = blockIdx.y;
    int n = blockIdx.z;
    int tid = threadIdx.x;
    int wave = tid >> 6, lane = tid & 63;
    int lrow = lane & 15, lq = lane >> 4;
    int lr8 = lane >> 3, lb = lane & 7;
    int swz = (lb ^ lr8) * 8;
    u16* psd = &PsPb[wave * 1664];

    // ---- Q fragments straight from global: aw = Q+rwb, ar = Q+rrb (bf16)
    bf16x8 aw[2], ar[2];
    {
        const u16* qrow = Qb + ((size_t)(n * SEQ + q0 + wave * 16 + lrow)) * EMB + h * HD;
#pragma unroll
        for (int ks = 0; ks < 2; ks++) {
            int c = ks * 32 + lq * 8;
            uint4 qv = *(const uint4*)(qrow + c);
            float4 w0 = *(const float4*)(rwb + h * HD + c);
            float4 w1 = *(const float4*)(rwb + h * HD + c + 4);
            float4 r0 = *(const float4*)(rrb + h * HD + c);
            float4 r1 = *(const float4*)(rrb + h * HD + c + 4);
            union { uint4 u; u16 s[8]; } qu; qu.u = qv;
            union { uint4 u; bf16x8 v; } ww, rr;
            ww.u.x = pack2(b2f(qu.s[0]) + w0.x, b2f(qu.s[1]) + w0.y);
            ww.u.y = pack2(b2f(qu.s[2]) + w0.z, b2f(qu.s[3]) + w0.w);
            ww.u.z = pack2(b2f(qu.s[4]) + w1.x, b2f(qu.s[5]) + w1.y);
            ww.u.w = pack2(b2f(qu.s[6]) + w1.z, b2f(qu.s[7]) + w1.w);
            rr.u.x = pack2(b2f(qu.s[0]) + r0.x, b2f(qu.s[1]) + r0.y);
            rr.u.y = pack2(b2f(qu.s[2]) + r0.z, b2f(qu.s[3]) + r0.w);
            rr.u.z = pack2(b2f(qu.s[4]) + r1.x, b2f(qu.s[5]) + r1.y);
            rr.u.w = pack2(b2f(qu.s[6]) + r1.z, b2f(qu.s[7]) + r1.w);
            aw[ks] = ww.v;
            ar[ks] = rr.v;
        }
    }

    auto stage_chunk = [&](int cc) {
#pragma unroll
        for (int j = 0; j < 2; j++) {      // K tile [kv][d]
            int row = j * 32 + wave * 8 + lr8;
            gl_lds16(Kb + ((size_t)(n * SEQ + cc + row)) * EMB + h * HD + swz,
                     &Ks[(j * 32 + wave * 8) * 64]);
        }
#pragma unroll
        for (int j = 0; j < 2; j++) {      // V^T tile [d][kv]
            int row = j * 32 + wave * 8 + lr8;
            gl_lds16(Vtg + (((size_t)(n * NH + h) * HD + row) << 9) + cc + swz,
                     &Vt[(j * 32 + wave * 8) * 64]);
        }
#pragma unroll
        for (int j = 0; j < 4; j++) {      // R band rows t0..t0+127, t0 = q0-cc+448 in [0,1023]
            int row = j * 32 + wave * 8 + lr8;
            gl_lds16(Rb + (size_t)(q0 - cc + 448 + row) * EMB + h * HD + swz,
                     &Rs[(j * 32 + wave * 8) * 64]);
        }
    };

    float lsum = 0.f;
    f32x4 acco[4] = {};

    stage_chunk(0);
    for (int c0 = 0; c0 < SEQ; c0 += 64) {
        __syncthreads();  // staging complete (vmcnt drained at barrier); prior LDS reads done

        f32x4 sacc[4] = {};
        f32x4 pacc[5] = {};
        bf16x8 vf[2][4];
#pragma unroll
        for (int ks = 0; ks < 2; ks++) {
            int pb = (ks * 4 + lq) ^ (lrow & 7);
#pragma unroll
            for (int ct = 0; ct < 4; ct++) {
                bf16x8 bk = *(const bf16x8*)&Ks[(ct * 16 + lrow) * 64 + pb * 8];
                // swapped: A = K-tile rows (kv), B = Q rows -> D[kv][q]
                sacc[ct] = __builtin_amdgcn_mfma_f32_16x16x32_bf16(bk, aw[ks], sacc[ct], 0, 0, 0);
            }
#pragma unroll
            for (int jj = 0; jj < 5; jj++) {
                bf16x8 br = *(const bf16x8*)&Rs[((wave + jj) * 16 + lrow) * 64 + pb * 8];
                pacc[jj] = __builtin_amdgcn_mfma_f32_16x16x32_bf16(ar[ks], br, pacc[jj], 0, 0, 0);
            }
#pragma unroll
            for (int dt = 0; dt < 4; dt++)
                vf[ks][dt] = *(const bf16x8*)&Vt[(dt * 16 + lrow) * 64 + pb * 8];
        }
        __syncthreads();  // all waves done reading Ks/Vt/Rs
        if (c0 + 64 < SEQ) stage_chunk(c0 + 64);  // overlaps the softmax/PV phase below

        // scatter banded P transposed: Psd[jwin][qlocal], one b64 per jj (wave-private region)
#pragma unroll
        for (int jj = 0; jj < 5; jj++) {
            uint2 pk2;
            pk2.x = cvtpk(pacc[jj][0], pacc[jj][1]);
            pk2.y = cvtpk(pacc[jj][2], pacc[jj][3]);
            *(uint2*)&psd[(jj * 16 + lrow) * 20 + lq * 4] = pk2;
        }
        cfence();  // scatter stores must complete (program order) before gather loads

        // gather bd for the SWAPPED layout: this lane owns (k = ct*16+lq*4+r, q = lrow)
        float bd[4][4];
#pragma unroll
        for (int ct = 0; ct < 4; ct++)
#pragma unroll
            for (int r = 0; r < 4; r++) {
                int jwin = lrow - (ct * 16 + lq * 4 + r) + 63;  // in [0,78]
                bd[ct][r] = b2f(psd[jwin * 20 + lrow]);
            }
        cfence();  // all gathers read before Pb stores overwrite the region

        // p = 2^((ac+bd)*0.125/ln2) (no max subtraction), per-lane row partial (q=lrow),
        // vectorized store Pb[qlocal][k]: lane's 4 k are consecutive -> one b64 per ct
#pragma unroll
        for (int ct = 0; ct < 4; ct++) {
            float p0 = exp2f((sacc[ct][0] + bd[ct][0]) * 0.18033688011f);
            float p1 = exp2f((sacc[ct][1] + bd[ct][1]) * 0.18033688011f);
            float p2 = exp2f((sacc[ct][2] + bd[ct][2]) * 0.18033688011f);
            float p3 = exp2f((sacc[ct][3] + bd[ct][3]) * 0.18033688011f);
            lsum += (p0 + p1) + (p2 + p3);
            uint2 pk2;
            pk2.x = cvtpk(p0, p1);
            pk2.y = cvtpk(p2, p3);
            *(uint2*)&psd[lrow * 72 + ct * 16 + lq * 4] = pk2;
        }
        cfence();  // Pb stores complete before PV fragment loads

        // PV operand-swapped: A = V-frag (d rows), B = P-frag (q rows) -> acco[dt] = O[d][q]
#pragma unroll
        for (int ks = 0; ks < 2; ks++) {
            bf16x8 pf = *(const bf16x8*)&psd[lrow * 72 + ks * 32 + lq * 8];
#pragma unroll
            for (int dt = 0; dt < 4; dt++)
                acco[dt] = __builtin_amdgcn_mfma_f32_16x16x32_bf16(vf[ks][dt], pf, acco[dt], 0, 0, 0);
        }
    }

    // epilogue: lane's partial is for q = lrow; reduce across the 4 lq-groups, no LDS needed
    lsum += __shfl_xor(lsum, 16);
    lsum += __shfl_xor(lsum, 32);
    float inv = 1.0f / lsum;
    int q = q0 + wave * 16 + lrow;
#pragma unroll
    for (int dt = 0; dt < 4; dt++) {
        ushort4 pk;
        pk.x = f2b(acco[dt][0] * inv);
        pk.y = f2b(acco[dt][1] * inv);
        pk.z = f2b(acco[dt][2] * inv);
        pk.w = f2b(acco[dt][3] * inv);
        *(ushort4*)&Ctx[((size_t)(n * SEQ + q)) * EMB + h * HD + dt * 16 + lq * 4] = pk;
    }
}

// ----------------------------------------------------------------
extern "C" void kernel_launch(void* const* d_in, const int* in_sizes, int n_in,
                              void* d_out, int out_size, void* d_ws, size_t ws_size,
                              hipStream_t stream) {
    const float* values = (const float*)d_in[0];
    const float* keys   = (const float*)d_in[1];
    const float* query  = (const float*)d_in[2];
    const float* Wq = (const float*)d_in[3];
    const float* bq = (const float*)d_in[4];
    const float* Wk = (const float*)d_in[5];
    const float* bk = (const float*)d_in[6];
    const float* Wv = (const float*)d_in[7];
    const float* bv = (const float*)d_in[8];
    const float* Wo = (const float*)d_in[9];
    const float* bo = (const float*)d_in[10];
    const float* Wpos = (const float*)d_in[11];
    const float* bpos = (const float*)d_in[12];
    const float* rwb = (const float*)d_in[13];
    const float* rrb = (const float*)d_in[14];
    float* out = (float*)d_out;

    u16* ws = (u16*)d_ws;
    size_t off = 0;
    u16* Wt = ws;            off += (size_t)5 * EMB * EMB;   // Wq^T,Wk^T,Wv^T,Wo^T,Wpos^T (bf16)
    u16* pe = ws + off;      off += (size_t)PEROWS * EMB;
    u16* Rb = ws + off;      off += (size_t)PEROWS * EMB;
    u16* qc = ws + off;      off += (size_t)NLROWS * EMB;    // bf16 query
    u16* kc = ws + off;      off += (size_t)NLROWS * EMB;    // bf16 keys
    u16* vc = ws + off;      off += (size_t)NLROWS * EMB;    // bf16 values
    u16* Qp = ws + off;      off += (size_t)NLROWS * EMB;    // Q projection
    u16* Kp = ws + off;      off += (size_t)NLROWS * EMB;    // K projection
    u16* Vtg = ws + off;     off += (size_t)NLROWS * EMB;    // V^T per (n,h): [n][h][d][kv]
    u16* Cx = qc;            // attention output (qc dead after fused GEMM dispatch)

    prep<<<dim3(8512), dim3(256), 0, stream>>>(Wq, Wk, Wv, Wo, Wpos, Wt, pe,
                                               query, keys, values, qc, kc, vc);

    // fused Q/K/V/R projection GEMMs: z = 0:Q 1:K 2:V(->V^T) 3:R(pe@Wpos, 1024 rows)
    // 128x128 tile: MFMA:DS 32:16 per wave-iter, grid (32,6,4) = 768 blocks = 3/CU.
    gemm_k<128, 128, 4, false><<<dim3(32, 6, 4), dim3(256), 0, stream>>>(
        qc, kc, vc, pe,
        Wt, Wt + (size_t)1 * EMB * EMB, Wt + (size_t)2 * EMB * EMB, Wt + (size_t)4 * EMB * EMB,
        bq, bk, bv, bpos,
        Qp, Kp, Vtg, Rb);

    attn_rpe<<<dim3(8, NH, NB), dim3(256), 0, stream>>>(Qp, Kp, Vtg, Rb, rwb, rrb, Cx);

    // output GEMM: 64x64 tiles -> 768 blocks = 3 blocks/CU (R12: beat 64x96's 2/CU).
    gemm_k<64, 64, 1, true><<<dim3(64, 12), dim3(256), 0, stream>>>(
        Cx, Cx, Cx, Cx,
        Wt + (size_t)3 * EMB * EMB, Wt + (size_t)3 * EMB * EMB,
        Wt + (size_t)3 * EMB * EMB, Wt + (size_t)3 * EMB * EMB,
        bo, bo, bo, bo,
        out, out, out, out);
}

// Round 12
// 173.009 us; speedup vs baseline: 1.0666x; 1.0025x over previous
//
#include <hip/hip_runtime.h>

typedef unsigned short u16;
typedef unsigned int u32;
typedef __bf16 bf16x8 __attribute__((ext_vector_type(8)));
typedef float f32x4 __attribute__((ext_vector_type(4)));

#define EMB 768
#define NH 12
#define HD 64
#define SEQ 512
#define NB 8
#define NLROWS 4096   // N*L
#define PEROWS 1024   // padded; row 1023 duplicates 1022 (only feeds unused MFMA lanes)

__device__ __forceinline__ float b2f(u16 u) {
    return __uint_as_float(((u32)u) << 16);
}
__device__ __forceinline__ u16 f2b(float f) {
    u32 x = __float_as_uint(f);
    u32 r = x + 0x7fffu + ((x >> 16) & 1u);
    return (u16)(r >> 16);
}
__device__ __forceinline__ u32 pack2(float a, float b) {
    return (u32)f2b(a) | ((u32)f2b(b) << 16);
}
// packed f32->bf16 (RNE), 1 VALU op instead of 6 — used only in attn hot loop
__device__ __forceinline__ u32 cvtpk(float lo, float hi) {
    u32 r;
    asm("v_cvt_pk_bf16_f32 %0, %1, %2" : "=v"(r) : "v"(lo), "v"(hi));
    return r;
}
// compiler-level memory fence: forbids cross-phase reordering of the type-punned
// psd LDS accesses (uint2 stores vs u16/bf16x8 loads -> TBAA would allow it).
__device__ __forceinline__ void cfence() { asm volatile("" ::: "memory"); }
// async global->LDS, 16B per lane; LDS dest = wave-uniform base + lane*16
__device__ __forceinline__ void gl_lds16(const u16* g, u16* l) {
    __builtin_amdgcn_global_load_lds((const __attribute__((address_space(1))) u32*)g,
                                     (__attribute__((address_space(3))) u32*)l, 16, 0, 0);
}

// ---------------------------------------------------------------- prep: transpose5 + pe + cvt3 in one launch
__global__ __launch_bounds__(256) void prep(
        const float* __restrict__ Wq, const float* __restrict__ Wk, const float* __restrict__ Wv,
        const float* __restrict__ Wo, const float* __restrict__ Wpos,
        u16* __restrict__ Wt, u16* __restrict__ pe,
        const float* __restrict__ q, const float* __restrict__ k, const float* __restrict__ v,
        u16* __restrict__ qc, u16* __restrict__ kc, u16* __restrict__ vc) {
    __shared__ u16 tile[32][33];
    int b = blockIdx.x;
    int tid = threadIdx.x;
    if (b < 2880) {
        // transpose+bf16ify the 5 weight matrices
        int m = b / 576, r = b % 576;
        const float* src = (m == 0) ? Wq : (m == 1) ? Wk : (m == 2) ? Wv : (m == 3) ? Wo : Wpos;
        u16* dst = Wt + (size_t)m * EMB * EMB;
        int bx = (r % 24) * 32, by = (r / 24) * 32;
        int tx = tid & 31, ty = tid >> 5;
#pragma unroll
        for (int i = 0; i < 32; i += 8)
            tile[ty + i][tx] = f2b(src[(size_t)(by + ty + i) * EMB + bx + tx]);
        __syncthreads();
        // write side: 2 consecutive out-cols per lane -> u32 stores (2x wider than scalar u16)
        int c2 = (tid & 15) * 2, rw = tid >> 4;
#pragma unroll
        for (int i = 0; i < 32; i += 16) {
            int row = rw + i;
            u32 val = (u32)tile[c2][row] | ((u32)tile[c2 + 1][row] << 16);
            *(u32*)&dst[(size_t)(bx + row) * EMB + by + c2] = val;
        }
    } else if (b < 3904) {
        // sinusoid table rows 0..1023 (1023 dup of 1022)
        int pos = b - 2880;
        int p2 = pos > 1022 ? 1022 : pos;
#pragma unroll
        for (int j = 0; j < 3; j++) {
            int col = tid + j * 256;
            int i = col >> 1;
            float ang = (float)p2 * __expf(-0.023985261384f * (float)i);
            float val = (col & 1) ? __cosf(ang) : __sinf(ang);
            pe[(size_t)pos * EMB + col] = f2b(val);
        }
    } else {
        // fp32 -> bf16 bulk convert q,k,v
        int idx = b - 3904;              // [0, 4608)
        int w = idx / 1536, bx = idx % 1536;
        const float* s = (w == 0) ? q : (w == 1) ? k : v;
        u16* d = (w == 0) ? qc : (w == 1) ? kc : vc;
        size_t i = ((size_t)bx * 256 + tid) * 8;
        float4 f0 = *(const float4*)(s + i);
        float4 f1 = *(const float4*)(s + i + 4);
        uint4 o;
        o.x = pack2(f0.x, f0.y); o.y = pack2(f0.z, f0.w);
        o.z = pack2(f1.x, f1.y); o.w = pack2(f1.z, f1.w);
        *(uint4*)(d + i) = o;
    }
}

// ---------------------------------------------------------------- C[M,768] = A[M,768] @ Bt^T + bias
// BM x BN tile, BK=64, XOR-swizzled unpadded LDS, global_load_lds staging.
// NZ=4: PACKED 1-D x-grid: x in [0, 3*TPM) -> z = x/TPM (Q/K/V, 4096 rows each);
// x in [3*TPM, 3*TPM+PEROWS/BM) -> z = 3 (R GEMM, 1024 rows). No idle blocks
// (was (32,6,4) = 768 blocks with 144 early-returns; now (104,6) = 624, all working).
// z==2 writes V^T layout. launch_bounds (256,3): 128x128 needs ~115 VGPR.
template <int BM, int BN, int NZ, bool OUTF32>
__global__ __launch_bounds__(256, 3) void gemm_k(
        const u16* A0, const u16* A1, const u16* A2, const u16* A3,
        const u16* W0, const u16* W1, const u16* W2, const u16* W3,
        const float* f0, const float* f1, const float* f2, const float* f3,
        void* C0, void* C1, void* C2, void* C3) {
    constexpr int RT = BM / 32;          // row tiles of 16 per wave
    constexpr int CT = BN / 32;          // col tiles of 16 per wave
    __shared__ __align__(16) u16 As[BM * 64];
    __shared__ __align__(16) u16 Bs[BN * 64];
    int z, m0;
    if (NZ > 1) {
        constexpr int TPM = NLROWS / BM;   // tiles per 4096-row matrix (32 at BM=128)
        int x = blockIdx.x;
        if (x < 3 * TPM) { z = x / TPM; m0 = (x % TPM) * BM; }
        else             { z = 3;       m0 = (x - 3 * TPM) * BM; }
    } else {
        z = 0; m0 = blockIdx.x * BM;
    }
    const u16* A = (z == 0) ? A0 : (z == 1) ? A1 : (z == 2) ? A2 : A3;
    const u16* Bt = (z == 0) ? W0 : (z == 1) ? W1 : (z == 2) ? W2 : W3;
    const float* bias = (z == 0) ? f0 : (z == 1) ? f1 : (z == 2) ? f2 : f3;
    void* Cv = (z == 0) ? C0 : (z == 1) ? C1 : (z == 2) ? C2 : C3;
    bool vtout = (NZ > 1) && (z == 2);

    int tid = threadIdx.x;
    int wave = tid >> 6, lane = tid & 63;
    int lrow = lane & 15, lq = lane >> 4;
    int lr8 = lane >> 3, lb = lane & 7;
    int n0 = blockIdx.y * BN;
    int wr = (wave >> 1) * (BM / 2), wc = (wave & 1) * (BN / 2);
    const u16* Abase = A + (size_t)m0 * EMB + (size_t)(lb ^ lr8) * 8;
    const u16* Bbase = Bt + (size_t)n0 * EMB + (size_t)(lb ^ lr8) * 8;
    f32x4 acc[RT][CT] = {};

    for (int k0 = 0; k0 < EMB; k0 += 64) {
        __syncthreads();
#pragma unroll
        for (int j = 0; j < BM / 32; j++) {
            int row = j * 32 + wave * 8 + lr8;
            gl_lds16(Abase + (size_t)row * EMB + k0, &As[(j * 32 + wave * 8) * 64]);
        }
#pragma unroll
        for (int j = 0; j < BN / 32; j++) {
            int row = j * 32 + wave * 8 + lr8;
            gl_lds16(Bbase + (size_t)row * EMB + k0, &Bs[(j * 32 + wave * 8) * 64]);
        }
        __syncthreads();
#pragma unroll
        for (int ks = 0; ks < 2; ks++) {
            int pb = (ks * 4 + lq) ^ (lrow & 7);
            bf16x8 bfr[CT];
#pragma unroll
            for (int ct = 0; ct < CT; ct++)
                bfr[ct] = *(const bf16x8*)&Bs[(wc + ct * 16 + lrow) * 64 + pb * 8];
#pragma unroll
            for (int rt = 0; rt < RT; rt++) {
                bf16x8 afr = *(const bf16x8*)&As[(wr + rt * 16 + lrow) * 64 + pb * 8];
#pragma unroll
                for (int ct = 0; ct < CT; ct++)
                    acc[rt][ct] = __builtin_amdgcn_mfma_f32_16x16x32_bf16(afr, bfr[ct], acc[rt][ct], 0, 0, 0);
            }
        }
    }
#pragma unroll
    for (int rt = 0; rt < RT; rt++) {
#pragma unroll
        for (int ct = 0; ct < CT; ct++) {
            int col = n0 + wc + ct * 16 + lrow;
            float bvv = bias[col];
            int mrow = m0 + wr + rt * 16 + lq * 4;
            if (vtout) {
                // V^T per (n,h): Vtg[((n*12+h)*64 + d)*512 + kv], 4 kv packed
                int nb = mrow >> 9, kvl = mrow & 511;
                int hh = col >> 6, dl = col & 63;
                ushort4 pk;
                pk.x = f2b(acc[rt][ct][0] + bvv);
                pk.y = f2b(acc[rt][ct][1] + bvv);
                pk.z = f2b(acc[rt][ct][2] + bvv);
                pk.w = f2b(acc[rt][ct][3] + bvv);
                *(ushort4*)((u16*)Cv + (((size_t)(nb * NH + hh) * HD + dl) << 9) + kvl) = pk;
            } else if (OUTF32) {
#pragma unroll
                for (int r = 0; r < 4; r++)
                    ((float*)Cv)[(size_t)(mrow + r) * EMB + col] = acc[rt][ct][r] + bvv;
            } else {
#pragma unroll
                for (int r = 0; r < 4; r++)
                    ((u16*)Cv)[(size_t)(mrow + r) * EMB + col] = f2b(acc[rt][ct][r] + bvv);
            }
        }
    }
}

// ---------------------------------------------------------------- fused attention (R18 = R15/R17, the 173.4us optimum)
// Structure lesson (R11/R13/R16, three-way confirmed): hipcc drains vmcnt(0) at every
// s_barrier, so in this 2-barrier loop ONLY global_load_lds staging is latency-free
// (drains while waves compute the previous chunk); any direct global load or extra
// VALU inside the barrier-to-barrier phases is fully exposed. Hence: staged Ks/Vt/Rs,
// offset-folded ds_reads, no setprio (R14: +1.5us), no circular-R (R13: -2.6us),
// no V/R-direct (R16/R11: -11us each), original dispatch grid (R10: remap -3us).
// cfences pin the psd type-punning order hazard (R8/R9 failures).
// Wave w owns q rows [w*16, w*16+16). QK^T operand-swapped (lane: k=lq*4+r, q=lrow).
__global__ __launch_bounds__(256, 3) void attn_rpe(
        const u16* __restrict__ Qb, const u16* __restrict__ Kb, const u16* __restrict__ Vtg,
        const u16* __restrict__ Rb, const float* __restrict__ rwb, const float* __restrict__ rrb,
        u16* __restrict__ Ctx) {
    __shared__ __align__(16) u16 Ks[64 * 64];
    __shared__ __align__(16) u16 Vt[64 * 64];
    __shared__ __align__(16) u16 Rs[128 * 64];
    // per-wave region (1664 u16 = 3328 B): Psd[80][20] (1600), later reused as Pb[16][72] (1152)
    __shared__ __align__(16) u16 PsPb[4 * 1664];

    int q0 = blockIdx.x * 64;
    int h = blockIdx.y;
    int n = blockIdx.z;
    int tid = threadIdx.x;
    int wave = tid >> 6, lane = tid & 63;
    int lrow = lane & 15, lq = lane >> 4;
    int lr8 = lane >> 3, lb = lane & 7;
    int swz = (lb ^ lr8) * 8;
    u16* psd = &PsPb[wave * 1664];

    // ---- Q fragments straight from global: aw = Q+rwb, ar = Q+rrb (bf16)
    bf16x8 aw[2], ar[2];
    {
        const u16* qrow = Qb + ((size_t)(n * SEQ + q0 + wave * 16 + lrow)) * EMB + h * HD;
#pragma unroll
        for (int ks = 0; ks < 2; ks++) {
            int c = ks * 32 + lq * 8;
            uint4 qv = *(const uint4*)(qrow + c);
            float4 w0 = *(const float4*)(rwb + h * HD + c);
            float4 w1 = *(const float4*)(rwb + h * HD + c + 4);
            float4 r0 = *(const float4*)(rrb + h * HD + c);
            float4 r1 = *(const float4*)(rrb + h * HD + c + 4);
            union { uint4 u; u16 s[8]; } qu; qu.u = qv;
            union { uint4 u; bf16x8 v; } ww, rr;
            ww.u.x = pack2(b2f(qu.s[0]) + w0.x, b2f(qu.s[1]) + w0.y);
            ww.u.y = pack2(b2f(qu.s[2]) + w0.z, b2f(qu.s[3]) + w0.w);
            ww.u.z = pack2(b2f(qu.s[4]) + w1.x, b2f(qu.s[5]) + w1.y);
            ww.u.w = pack2(b2f(qu.s[6]) + w1.z, b2f(qu.s[7]) + w1.w);
            rr.u.x = pack2(b2f(qu.s[0]) + r0.x, b2f(qu.s[1]) + r0.y);
            rr.u.y = pack2(b2f(qu.s[2]) + r0.z, b2f(qu.s[3]) + r0.w);
            rr.u.z = pack2(b2f(qu.s[4]) + r1.x, b2f(qu.s[5]) + r1.y);
            rr.u.w = pack2(b2f(qu.s[6]) + r1.z, b2f(qu.s[7]) + r1.w);
            aw[ks] = ww.v;
            ar[ks] = rr.v;
        }
    }

    auto stage_chunk = [&](int cc) {
#pragma unroll
        for (int j = 0; j < 2; j++) {      // K tile [kv][d]
            int row = j * 32 + wave * 8 + lr8;
            gl_lds16(Kb + ((size_t)(n * SEQ + cc + row)) * EMB + h * HD + swz,
                     &Ks[(j * 32 + wave * 8) * 64]);
        }
#pragma unroll
        for (int j = 0; j < 2; j++) {      // V^T tile [d][kv]
            int row = j * 32 + wave * 8 + lr8;
            gl_lds16(Vtg + (((size_t)(n * NH + h) * HD + row) << 9) + cc + swz,
                     &Vt[(j * 32 + wave * 8) * 64]);
        }
#pragma unroll
        for (int j = 0; j < 4; j++) {      // R band rows t0..t0+127, t0 = q0-cc+448 in [0,1023]
            int row = j * 32 + wave * 8 + lr8;
            gl_lds16(Rb + (size_t)(q0 - cc + 448 + row) * EMB + h * HD + swz,
                     &Rs[(j * 32 + wave * 8) * 64]);
        }
    };

    float lsum = 0.f;
    f32x4 acco[4] = {};

    stage_chunk(0);
    for (int c0 = 0; c0 < SEQ; c0 += 64) {
        __syncthreads();  // staging complete (vmcnt drained at barrier); prior LDS reads done

        f32x4 sacc[4] = {};
        f32x4 pacc[5] = {};
        bf16x8 vf[2][4];
#pragma unroll
        for (int ks = 0; ks < 2; ks++) {
            int pb = (ks * 4 + lq) ^ (lrow & 7);
#pragma unroll
            for (int ct = 0; ct < 4; ct++) {
                bf16x8 bk = *(const bf16x8*)&Ks[(ct * 16 + lrow) * 64 + pb * 8];
                // swapped: A = K-tile rows (kv), B = Q rows -> D[kv][q]
                sacc[ct] = __builtin_amdgcn_mfma_f32_16x16x32_bf16(bk, aw[ks], sacc[ct], 0, 0, 0);
            }
#pragma unroll
            for (int jj = 0; jj < 5; jj++) {
                bf16x8 br = *(const bf16x8*)&Rs[((wave + jj) * 16 + lrow) * 64 + pb * 8];
                pacc[jj] = __builtin_amdgcn_mfma_f32_16x16x32_bf16(ar[ks], br, pacc[jj], 0, 0, 0);
            }
#pragma unroll
            for (int dt = 0; dt < 4; dt++)
                vf[ks][dt] = *(const bf16x8*)&Vt[(dt * 16 + lrow) * 64 + pb * 8];
        }
        __syncthreads();  // all waves done reading Ks/Vt/Rs
        if (c0 + 64 < SEQ) stage_chunk(c0 + 64);  // overlaps the softmax/PV phase below

        // scatter banded P transposed: Psd[jwin][qlocal], one b64 per jj (wave-private region)
#pragma unroll
        for (int jj = 0; jj < 5; jj++) {
            uint2 pk2;
            pk2.x = cvtpk(pacc[jj][0], pacc[jj][1]);
            pk2.y = cvtpk(pacc[jj][2], pacc[jj][3]);
            *(uint2*)&psd[(jj * 16 + lrow) * 20 + lq * 4] = pk2;
        }
        cfence();  // scatter stores must complete (program order) before gather loads

        // gather bd for the SWAPPED layout: this lane owns (k = ct*16+lq*4+r, q = lrow)
        float bd[4][4];
#pragma unroll
        for (int ct = 0; ct < 4; ct++)
#pragma unroll
            for (int r = 0; r < 4; r++) {
                int jwin = lrow - (ct * 16 + lq * 4 + r) + 63;  // in [0,78]
                bd[ct][r] = b2f(psd[jwin * 20 + lrow]);
            }
        cfence();  // all gathers read before Pb stores overwrite the region

        // p = 2^((ac+bd)*0.125/ln2) (no max subtraction), per-lane row partial (q=lrow),
        // vectorized store Pb[qlocal][k]: lane's 4 k are consecutive -> one b64 per ct
#pragma unroll
        for (int ct = 0; ct < 4; ct++) {
            float p0 = exp2f((sacc[ct][0] + bd[ct][0]) * 0.18033688011f);
            float p1 = exp2f((sacc[ct][1] + bd[ct][1]) * 0.18033688011f);
            float p2 = exp2f((sacc[ct][2] + bd[ct][2]) * 0.18033688011f);
            float p3 = exp2f((sacc[ct][3] + bd[ct][3]) * 0.18033688011f);
            lsum += (p0 + p1) + (p2 + p3);
            uint2 pk2;
            pk2.x = cvtpk(p0, p1);
            pk2.y = cvtpk(p2, p3);
            *(uint2*)&psd[lrow * 72 + ct * 16 + lq * 4] = pk2;
        }
        cfence();  // Pb stores complete before PV fragment loads

        // PV operand-swapped: A = V-frag (d rows), B = P-frag (q rows) -> acco[dt] = O[d][q]
#pragma unroll
        for (int ks = 0; ks < 2; ks++) {
            bf16x8 pf = *(const bf16x8*)&psd[lrow * 72 + ks * 32 + lq * 8];
#pragma unroll
            for (int dt = 0; dt < 4; dt++)
                acco[dt] = __builtin_amdgcn_mfma_f32_16x16x32_bf16(vf[ks][dt], pf, acco[dt], 0, 0, 0);
        }
    }

    // epilogue: lane's partial is for q = lrow; reduce across the 4 lq-groups, no LDS needed
    lsum += __shfl_xor(lsum, 16);
    lsum += __shfl_xor(lsum, 32);
    float inv = 1.0f / lsum;
    int q = q0 + wave * 16 + lrow;
#pragma unroll
    for (int dt = 0; dt < 4; dt++) {
        ushort4 pk;
        pk.x = f2b(acco[dt][0] * inv);
        pk.y = f2b(acco[dt][1] * inv);
        pk.z = f2b(acco[dt][2] * inv);
        pk.w = f2b(acco[dt][3] * inv);
        *(ushort4*)&Ctx[((size_t)(n * SEQ + q)) * EMB + h * HD + dt * 16 + lq * 4] = pk;
    }
}

// ----------------------------------------------------------------
extern "C" void kernel_launch(void* const* d_in, const int* in_sizes, int n_in,
                              void* d_out, int out_size, void* d_ws, size_t ws_size,
                              hipStream_t stream) {
    const float* values = (const float*)d_in[0];
    const float* keys   = (const float*)d_in[1];
    const float* query  = (const float*)d_in[2];
    const float* Wq = (const float*)d_in[3];
    const float* bq = (const float*)d_in[4];
    const float* Wk = (const float*)d_in[5];
    const float* bk = (const float*)d_in[6];
    const float* Wv = (const float*)d_in[7];
    const float* bv = (const float*)d_in[8];
    const float* Wo = (const float*)d_in[9];
    const float* bo = (const float*)d_in[10];
    const float* Wpos = (const float*)d_in[11];
    const float* bpos = (const float*)d_in[12];
    const float* rwb = (const float*)d_in[13];
    const float* rrb = (const float*)d_in[14];
    float* out = (float*)d_out;

    u16* ws = (u16*)d_ws;
    size_t off = 0;
    u16* Wt = ws;            off += (size_t)5 * EMB * EMB;   // Wq^T,Wk^T,Wv^T,Wo^T,Wpos^T (bf16)
    u16* pe = ws + off;      off += (size_t)PEROWS * EMB;
    u16* Rb = ws + off;      off += (size_t)PEROWS * EMB;
    u16* qc = ws + off;      off += (size_t)NLROWS * EMB;    // bf16 query
    u16* kc = ws + off;      off += (size_t)NLROWS * EMB;    // bf16 keys
    u16* vc = ws + off;      off += (size_t)NLROWS * EMB;    // bf16 values
    u16* Qp = ws + off;      off += (size_t)NLROWS * EMB;    // Q projection
    u16* Kp = ws + off;      off += (size_t)NLROWS * EMB;    // K projection
    u16* Vtg = ws + off;     off += (size_t)NLROWS * EMB;    // V^T per (n,h): [n][h][d][kv]
    u16* Cx = qc;            // attention output (qc dead after fused GEMM dispatch)

    prep<<<dim3(8512), dim3(256), 0, stream>>>(Wq, Wk, Wv, Wo, Wpos, Wt, pe,
                                               query, keys, values, qc, kc, vc);

    // fused Q/K/V/R projection GEMMs, PACKED x-grid: x in [0,96) -> Q/K/V (z = x/32),
    // x in [96,104) -> R (1024 rows). 624 blocks, all working (was 768 with 144 no-ops).
    gemm_k<128, 128, 4, false><<<dim3(104, 6), dim3(256), 0, stream>>>(
        qc, kc, vc, pe,
        Wt, Wt + (size_t)1 * EMB * EMB, Wt + (size_t)2 * EMB * EMB, Wt + (size_t)4 * EMB * EMB,
        bq, bk, bv, bpos,
        Qp, Kp, Vtg, Rb);

    attn_rpe<<<dim3(8, NH, NB), dim3(256), 0, stream>>>(Qp, Kp, Vtg, Rb, rwb, rrb, Cx);

    // output GEMM: 64x64 tiles -> 768 blocks = 3 blocks/CU (R12: beat 64x96's 2/CU).
    gemm_k<64, 64, 1, true><<<dim3(64, 12), dim3(256), 0, stream>>>(
        Cx, Cx, Cx, Cx,
        Wt + (size_t)3 * EMB * EMB, Wt + (size_t)3 * EMB * EMB,
        Wt + (size_t)3 * EMB * EMB, Wt + (size_t)3 * EMB * EMB,
        bo, bo, bo, bo,
        out, out, out, out);
}

// Round 13
// 172.694 us; speedup vs baseline: 1.0686x; 1.0018x over previous
//
#include <hip/hip_runtime.h>

typedef unsigned short u16;
typedef unsigned int u32;
typedef __bf16 bf16x8 __attribute__((ext_vector_type(8)));
typedef float f32x4 __attribute__((ext_vector_type(4)));

#define EMB 768
#define NH 12
#define HD 64
#define SEQ 512
#define NB 8
#define NLROWS 4096   // N*L
#define PEROWS 1024   // padded; row 1023 duplicates 1022 (only feeds unused MFMA lanes)

__device__ __forceinline__ float b2f(u16 u) {
    return __uint_as_float(((u32)u) << 16);
}
__device__ __forceinline__ u16 f2b(float f) {
    u32 x = __float_as_uint(f);
    u32 r = x + 0x7fffu + ((x >> 16) & 1u);
    return (u16)(r >> 16);
}
__device__ __forceinline__ u32 pack2(float a, float b) {
    return (u32)f2b(a) | ((u32)f2b(b) << 16);
}
// packed f32->bf16 (RNE), 1 VALU op instead of 6 — used only in attn hot loop
__device__ __forceinline__ u32 cvtpk(float lo, float hi) {
    u32 r;
    asm("v_cvt_pk_bf16_f32 %0, %1, %2" : "=v"(r) : "v"(lo), "v"(hi));
    return r;
}
// compiler-level memory fence: forbids cross-phase reordering of the type-punned
// psd LDS accesses (uint2 stores vs u16/bf16x8 loads -> TBAA would allow it).
__device__ __forceinline__ void cfence() { asm volatile("" ::: "memory"); }
// async global->LDS, 16B per lane; LDS dest = wave-uniform base + lane*16
__device__ __forceinline__ void gl_lds16(const u16* g, u16* l) {
    __builtin_amdgcn_global_load_lds((const __attribute__((address_space(1))) u32*)g,
                                     (__attribute__((address_space(3))) u32*)l, 16, 0, 0);
}

// ---------------------------------------------------------------- prep: transpose5 + pe + cvt3 in one launch
__global__ __launch_bounds__(256) void prep(
        const float* __restrict__ Wq, const float* __restrict__ Wk, const float* __restrict__ Wv,
        const float* __restrict__ Wo, const float* __restrict__ Wpos,
        u16* __restrict__ Wt, u16* __restrict__ pe,
        const float* __restrict__ q, const float* __restrict__ k, const float* __restrict__ v,
        u16* __restrict__ qc, u16* __restrict__ kc, u16* __restrict__ vc) {
    __shared__ u16 tile[32][33];
    int b = blockIdx.x;
    int tid = threadIdx.x;
    if (b < 2880) {
        // transpose+bf16ify the 5 weight matrices
        int m = b / 576, r = b % 576;
        const float* src = (m == 0) ? Wq : (m == 1) ? Wk : (m == 2) ? Wv : (m == 3) ? Wo : Wpos;
        u16* dst = Wt + (size_t)m * EMB * EMB;
        int bx = (r % 24) * 32, by = (r / 24) * 32;
        int tx = tid & 31, ty = tid >> 5;
#pragma unroll
        for (int i = 0; i < 32; i += 8)
            tile[ty + i][tx] = f2b(src[(size_t)(by + ty + i) * EMB + bx + tx]);
        __syncthreads();
        // write side: 2 consecutive out-cols per lane -> u32 stores (2x wider than scalar u16)
        int c2 = (tid & 15) * 2, rw = tid >> 4;
#pragma unroll
        for (int i = 0; i < 32; i += 16) {
            int row = rw + i;
            u32 val = (u32)tile[c2][row] | ((u32)tile[c2 + 1][row] << 16);
            *(u32*)&dst[(size_t)(bx + row) * EMB + by + c2] = val;
        }
    } else if (b < 3904) {
        // sinusoid table rows 0..1023 (1023 dup of 1022)
        int pos = b - 2880;
        int p2 = pos > 1022 ? 1022 : pos;
#pragma unroll
        for (int j = 0; j < 3; j++) {
            int col = tid + j * 256;
            int i = col >> 1;
            float ang = (float)p2 * __expf(-0.023985261384f * (float)i);
            float val = (col & 1) ? __cosf(ang) : __sinf(ang);
            pe[(size_t)pos * EMB + col] = f2b(val);
        }
    } else {
        // fp32 -> bf16 bulk convert q,k,v
        int idx = b - 3904;              // [0, 4608)
        int w = idx / 1536, bx = idx % 1536;
        const float* s = (w == 0) ? q : (w == 1) ? k : v;
        u16* d = (w == 0) ? qc : (w == 1) ? kc : vc;
        size_t i = ((size_t)bx * 256 + tid) * 8;
        float4 f0 = *(const float4*)(s + i);
        float4 f1 = *(const float4*)(s + i + 4);
        uint4 o;
        o.x = pack2(f0.x, f0.y); o.y = pack2(f0.z, f0.w);
        o.z = pack2(f1.x, f1.y); o.w = pack2(f1.z, f1.w);
        *(uint4*)(d + i) = o;
    }
}

// ---------------------------------------------------------------- C[M,768] = A[M,768] @ Bt^T + bias
// BM x BN tile, BK=64, XOR-swizzled unpadded LDS, global_load_lds staging.
// NZ=4: PACKED 1-D x-grid: x in [0, 3*TPM) -> z = x/TPM (Q/K/V, 4096 rows each);
// x in [3*TPM, 3*TPM+PEROWS/BM) -> z = 3 (R GEMM, 1024 rows). No idle blocks.
// z==2 writes V^T layout. launch_bounds (256,3): 128x128 needs ~115 VGPR.
template <int BM, int BN, int NZ, bool OUTF32>
__global__ __launch_bounds__(256, 3) void gemm_k(
        const u16* A0, const u16* A1, const u16* A2, const u16* A3,
        const u16* W0, const u16* W1, const u16* W2, const u16* W3,
        const float* f0, const float* f1, const float* f2, const float* f3,
        void* C0, void* C1, void* C2, void* C3) {
    constexpr int RT = BM / 32;          // row tiles of 16 per wave
    constexpr int CT = BN / 32;          // col tiles of 16 per wave
    __shared__ __align__(16) u16 As[BM * 64];
    __shared__ __align__(16) u16 Bs[BN * 64];
    int z, m0;
    if (NZ > 1) {
        constexpr int TPM = NLROWS / BM;   // tiles per 4096-row matrix (32 at BM=128)
        int x = blockIdx.x;
        if (x < 3 * TPM) { z = x / TPM; m0 = (x % TPM) * BM; }
        else             { z = 3;       m0 = (x - 3 * TPM) * BM; }
    } else {
        z = 0; m0 = blockIdx.x * BM;
    }
    const u16* A = (z == 0) ? A0 : (z == 1) ? A1 : (z == 2) ? A2 : A3;
    const u16* Bt = (z == 0) ? W0 : (z == 1) ? W1 : (z == 2) ? W2 : W3;
    const float* bias = (z == 0) ? f0 : (z == 1) ? f1 : (z == 2) ? f2 : f3;
    void* Cv = (z == 0) ? C0 : (z == 1) ? C1 : (z == 2) ? C2 : C3;
    bool vtout = (NZ > 1) && (z == 2);

    int tid = threadIdx.x;
    int wave = tid >> 6, lane = tid & 63;
    int lrow = lane & 15, lq = lane >> 4;
    int lr8 = lane >> 3, lb = lane & 7;
    int n0 = blockIdx.y * BN;
    int wr = (wave >> 1) * (BM / 2), wc = (wave & 1) * (BN / 2);
    const u16* Abase = A + (size_t)m0 * EMB + (size_t)(lb ^ lr8) * 8;
    const u16* Bbase = Bt + (size_t)n0 * EMB + (size_t)(lb ^ lr8) * 8;
    f32x4 acc[RT][CT] = {};

    for (int k0 = 0; k0 < EMB; k0 += 64) {
        __syncthreads();
#pragma unroll
        for (int j = 0; j < BM / 32; j++) {
            int row = j * 32 + wave * 8 + lr8;
            gl_lds16(Abase + (size_t)row * EMB + k0, &As[(j * 32 + wave * 8) * 64]);
        }
#pragma unroll
        for (int j = 0; j < BN / 32; j++) {
            int row = j * 32 + wave * 8 + lr8;
            gl_lds16(Bbase + (size_t)row * EMB + k0, &Bs[(j * 32 + wave * 8) * 64]);
        }
        __syncthreads();
#pragma unroll
        for (int ks = 0; ks < 2; ks++) {
            int pb = (ks * 4 + lq) ^ (lrow & 7);
            bf16x8 bfr[CT];
#pragma unroll
            for (int ct = 0; ct < CT; ct++)
                bfr[ct] = *(const bf16x8*)&Bs[(wc + ct * 16 + lrow) * 64 + pb * 8];
#pragma unroll
            for (int rt = 0; rt < RT; rt++) {
                bf16x8 afr = *(const bf16x8*)&As[(wr + rt * 16 + lrow) * 64 + pb * 8];
#pragma unroll
                for (int ct = 0; ct < CT; ct++)
                    acc[rt][ct] = __builtin_amdgcn_mfma_f32_16x16x32_bf16(afr, bfr[ct], acc[rt][ct], 0, 0, 0);
            }
        }
    }
#pragma unroll
    for (int rt = 0; rt < RT; rt++) {
#pragma unroll
        for (int ct = 0; ct < CT; ct++) {
            int col = n0 + wc + ct * 16 + lrow;
            float bvv = bias[col];
            int mrow = m0 + wr + rt * 16 + lq * 4;
            if (vtout) {
                // V^T per (n,h): Vtg[((n*12+h)*64 + d)*512 + kv], 4 kv packed
                int nb = mrow >> 9, kvl = mrow & 511;
                int hh = col >> 6, dl = col & 63;
                ushort4 pk;
                pk.x = f2b(acc[rt][ct][0] + bvv);
                pk.y = f2b(acc[rt][ct][1] + bvv);
                pk.z = f2b(acc[rt][ct][2] + bvv);
                pk.w = f2b(acc[rt][ct][3] + bvv);
                *(ushort4*)((u16*)Cv + (((size_t)(nb * NH + hh) * HD + dl) << 9) + kvl) = pk;
            } else if (OUTF32) {
#pragma unroll
                for (int r = 0; r < 4; r++)
                    ((float*)Cv)[(size_t)(mrow + r) * EMB + col] = acc[rt][ct][r] + bvv;
            } else {
#pragma unroll
                for (int r = 0; r < 4; r++)
                    ((u16*)Cv)[(size_t)(mrow + r) * EMB + col] = f2b(acc[rt][ct][r] + bvv);
            }
        }
    }
}

// ---------------------------------------------------------------- fused attention (converged optimum, 173.0us)
// Structure lesson (R11/R13/R16, three-way confirmed): hipcc drains vmcnt(0) at every
// s_barrier, so in this 2-barrier loop ONLY global_load_lds staging is latency-free
// (drains while waves compute the previous chunk); any direct global load or extra
// VALU inside the barrier-to-barrier phases is fully exposed. Hence: staged Ks/Vt/Rs,
// offset-folded ds_reads, no setprio (R14: +1.5us), no circular-R (R13: -2.6us),
// no V/R-direct (R16/R11: -11us each), original dispatch grid (R10: remap -3us).
// cfences pin the psd type-punning order hazard (R8/R9 failures).
// Wave w owns q rows [w*16, w*16+16). QK^T operand-swapped (lane: k=lq*4+r, q=lrow).
__global__ __launch_bounds__(256, 3) void attn_rpe(
        const u16* __restrict__ Qb, const u16* __restrict__ Kb, const u16* __restrict__ Vtg,
        const u16* __restrict__ Rb, const float* __restrict__ rwb, const float* __restrict__ rrb,
        u16* __restrict__ Ctx) {
    __shared__ __align__(16) u16 Ks[64 * 64];
    __shared__ __align__(16) u16 Vt[64 * 64];
    __shared__ __align__(16) u16 Rs[128 * 64];
    // per-wave region (1664 u16 = 3328 B): Psd[80][20] (1600), later reused as Pb[16][72] (1152)
    __shared__ __align__(16) u16 PsPb[4 * 1664];

    int q0 = blockIdx.x * 64;
    int h = blockIdx.y;
    int n = blockIdx.z;
    int tid = threadIdx.x;
    int wave = tid >> 6, lane = tid & 63;
    int lrow = lane & 15, lq = lane >> 4;
    int lr8 = lane >> 3, lb = lane & 7;
    int swz = (lb ^ lr8) * 8;
    u16* psd = &PsPb[wave * 1664];

    // ---- Q fragments straight from global: aw = Q+rwb, ar = Q+rrb (bf16)
    bf16x8 aw[2], ar[2];
    {
        const u16* qrow = Qb + ((size_t)(n * SEQ + q0 + wave * 16 + lrow)) * EMB + h * HD;
#pragma unroll
        for (int ks = 0; ks < 2; ks++) {
            int c = ks * 32 + lq * 8;
            uint4 qv = *(const uint4*)(qrow + c);
            float4 w0 = *(const float4*)(rwb + h * HD + c);
            float4 w1 = *(const float4*)(rwb + h * HD + c + 4);
            float4 r0 = *(const float4*)(rrb + h * HD + c);
            float4 r1 = *(const float4*)(rrb + h * HD + c + 4);
            union { uint4 u; u16 s[8]; } qu; qu.u = qv;
            union { uint4 u; bf16x8 v; } ww, rr;
            ww.u.x = pack2(b2f(qu.s[0]) + w0.x, b2f(qu.s[1]) + w0.y);
            ww.u.y = pack2(b2f(qu.s[2]) + w0.z, b2f(qu.s[3]) + w0.w);
            ww.u.z = pack2(b2f(qu.s[4]) + w1.x, b2f(qu.s[5]) + w1.y);
            ww.u.w = pack2(b2f(qu.s[6]) + w1.z, b2f(qu.s[7]) + w1.w);
            rr.u.x = pack2(b2f(qu.s[0]) + r0.x, b2f(qu.s[1]) + r0.y);
            rr.u.y = pack2(b2f(qu.s[2]) + r0.z, b2f(qu.s[3]) + r0.w);
            rr.u.z = pack2(b2f(qu.s[4]) + r1.x, b2f(qu.s[5]) + r1.y);
            rr.u.w = pack2(b2f(qu.s[6]) + r1.z, b2f(qu.s[7]) + r1.w);
            aw[ks] = ww.v;
            ar[ks] = rr.v;
        }
    }

    auto stage_chunk = [&](int cc) {
#pragma unroll
        for (int j = 0; j < 2; j++) {      // K tile [kv][d]
            int row = j * 32 + wave * 8 + lr8;
            gl_lds16(Kb + ((size_t)(n * SEQ + cc + row)) * EMB + h * HD + swz,
                     &Ks[(j * 32 + wave * 8) * 64]);
        }
#pragma unroll
        for (int j = 0; j < 2; j++) {      // V^T tile [d][kv]
            int row = j * 32 + wave * 8 + lr8;
            gl_lds16(Vtg + (((size_t)(n * NH + h) * HD + row) << 9) + cc + swz,
                     &Vt[(j * 32 + wave * 8) * 64]);
        }
#pragma unroll
        for (int j = 0; j < 4; j++) {      // R band rows t0..t0+127, t0 = q0-cc+448 in [0,1023]
            int row = j * 32 + wave * 8 + lr8;
            gl_lds16(Rb + (size_t)(q0 - cc + 448 + row) * EMB + h * HD + swz,
                     &Rs[(j * 32 + wave * 8) * 64]);
        }
    };

    float lsum = 0.f;
    f32x4 acco[4] = {};

    stage_chunk(0);
    for (int c0 = 0; c0 < SEQ; c0 += 64) {
        __syncthreads();  // staging complete (vmcnt drained at barrier); prior LDS reads done

        f32x4 sacc[4] = {};
        f32x4 pacc[5] = {};
        bf16x8 vf[2][4];
#pragma unroll
        for (int ks = 0; ks < 2; ks++) {
            int pb = (ks * 4 + lq) ^ (lrow & 7);
#pragma unroll
            for (int ct = 0; ct < 4; ct++) {
                bf16x8 bk = *(const bf16x8*)&Ks[(ct * 16 + lrow) * 64 + pb * 8];
                // swapped: A = K-tile rows (kv), B = Q rows -> D[kv][q]
                sacc[ct] = __builtin_amdgcn_mfma_f32_16x16x32_bf16(bk, aw[ks], sacc[ct], 0, 0, 0);
            }
#pragma unroll
            for (int jj = 0; jj < 5; jj++) {
                bf16x8 br = *(const bf16x8*)&Rs[((wave + jj) * 16 + lrow) * 64 + pb * 8];
                pacc[jj] = __builtin_amdgcn_mfma_f32_16x16x32_bf16(ar[ks], br, pacc[jj], 0, 0, 0);
            }
#pragma unroll
            for (int dt = 0; dt < 4; dt++)
                vf[ks][dt] = *(const bf16x8*)&Vt[(dt * 16 + lrow) * 64 + pb * 8];
        }
        __syncthreads();  // all waves done reading Ks/Vt/Rs
        if (c0 + 64 < SEQ) stage_chunk(c0 + 64);  // overlaps the softmax/PV phase below

        // scatter banded P transposed: Psd[jwin][qlocal], one b64 per jj (wave-private region)
#pragma unroll
        for (int jj = 0; jj < 5; jj++) {
            uint2 pk2;
            pk2.x = cvtpk(pacc[jj][0], pacc[jj][1]);
            pk2.y = cvtpk(pacc[jj][2], pacc[jj][3]);
            *(uint2*)&psd[(jj * 16 + lrow) * 20 + lq * 4] = pk2;
        }
        cfence();  // scatter stores must complete (program order) before gather loads

        // gather bd for the SWAPPED layout: this lane owns (k = ct*16+lq*4+r, q = lrow)
        float bd[4][4];
#pragma unroll
        for (int ct = 0; ct < 4; ct++)
#pragma unroll
            for (int r = 0; r < 4; r++) {
                int jwin = lrow - (ct * 16 + lq * 4 + r) + 63;  // in [0,78]
                bd[ct][r] = b2f(psd[jwin * 20 + lrow]);
            }
        cfence();  // all gathers read before Pb stores overwrite the region

        // p = 2^((ac+bd)*0.125/ln2) (no max subtraction), per-lane row partial (q=lrow),
        // vectorized store Pb[qlocal][k]: lane's 4 k are consecutive -> one b64 per ct
#pragma unroll
        for (int ct = 0; ct < 4; ct++) {
            float p0 = exp2f((sacc[ct][0] + bd[ct][0]) * 0.18033688011f);
            float p1 = exp2f((sacc[ct][1] + bd[ct][1]) * 0.18033688011f);
            float p2 = exp2f((sacc[ct][2] + bd[ct][2]) * 0.18033688011f);
            float p3 = exp2f((sacc[ct][3] + bd[ct][3]) * 0.18033688011f);
            lsum += (p0 + p1) + (p2 + p3);
            uint2 pk2;
            pk2.x = cvtpk(p0, p1);
            pk2.y = cvtpk(p2, p3);
            *(uint2*)&psd[lrow * 72 + ct * 16 + lq * 4] = pk2;
        }
        cfence();  // Pb stores complete before PV fragment loads

        // PV operand-swapped: A = V-frag (d rows), B = P-frag (q rows) -> acco[dt] = O[d][q]
#pragma unroll
        for (int ks = 0; ks < 2; ks++) {
            bf16x8 pf = *(const bf16x8*)&psd[lrow * 72 + ks * 32 + lq * 8];
#pragma unroll
            for (int dt = 0; dt < 4; dt++)
                acco[dt] = __builtin_amdgcn_mfma_f32_16x16x32_bf16(vf[ks][dt], pf, acco[dt], 0, 0, 0);
        }
    }

    // epilogue: lane's partial is for q = lrow; reduce across the 4 lq-groups, no LDS needed
    lsum += __shfl_xor(lsum, 16);
    lsum += __shfl_xor(lsum, 32);
    float inv = 1.0f / lsum;
    int q = q0 + wave * 16 + lrow;
#pragma unroll
    for (int dt = 0; dt < 4; dt++) {
        ushort4 pk;
        pk.x = f2b(acco[dt][0] * inv);
        pk.y = f2b(acco[dt][1] * inv);
        pk.z = f2b(acco[dt][2] * inv);
        pk.w = f2b(acco[dt][3] * inv);
        *(ushort4*)&Ctx[((size_t)(n * SEQ + q)) * EMB + h * HD + dt * 16 + lq * 4] = pk;
    }
}

// ----------------------------------------------------------------
extern "C" void kernel_launch(void* const* d_in, const int* in_sizes, int n_in,
                              void* d_out, int out_size, void* d_ws, size_t ws_size,
                              hipStream_t stream) {
    const float* values = (const float*)d_in[0];
    const float* keys   = (const float*)d_in[1];
    const float* query  = (const float*)d_in[2];
    const float* Wq = (const float*)d_in[3];
    const float* bq = (const float*)d_in[4];
    const float* Wk = (const float*)d_in[5];
    const float* bk = (const float*)d_in[6];
    const float* Wv = (const float*)d_in[7];
    const float* bv = (const float*)d_in[8];
    const float* Wo = (const float*)d_in[9];
    const float* bo = (const float*)d_in[10];
    const float* Wpos = (const float*)d_in[11];
    const float* bpos = (const float*)d_in[12];
    const float* rwb = (const float*)d_in[13];
    const float* rrb = (const float*)d_in[14];
    float* out = (float*)d_out;

    u16* ws = (u16*)d_ws;
    size_t off = 0;
    u16* Wt = ws;            off += (size_t)5 * EMB * EMB;   // Wq^T,Wk^T,Wv^T,Wo^T,Wpos^T (bf16)
    u16* pe = ws + off;      off += (size_t)PEROWS * EMB;
    u16* Rb = ws + off;      off += (size_t)PEROWS * EMB;
    u16* qc = ws + off;      off += (size_t)NLROWS * EMB;    // bf16 query
    u16* kc = ws + off;      off += (size_t)NLROWS * EMB;    // bf16 keys
    u16* vc = ws + off;      off += (size_t)NLROWS * EMB;    // bf16 values
    u16* Qp = ws + off;      off += (size_t)NLROWS * EMB;    // Q projection
    u16* Kp = ws + off;      off += (size_t)NLROWS * EMB;    // K projection
    u16* Vtg = ws + off;     off += (size_t)NLROWS * EMB;    // V^T per (n,h): [n][h][d][kv]
    u16* Cx = qc;            // attention output (qc dead after fused GEMM dispatch)

    prep<<<dim3(8512), dim3(256), 0, stream>>>(Wq, Wk, Wv, Wo, Wpos, Wt, pe,
                                               query, keys, values, qc, kc, vc);

    // fused Q/K/V/R projection GEMMs, PACKED x-grid: x in [0,96) -> Q/K/V (z = x/32),
    // x in [96,104) -> R (1024 rows). 624 blocks, all working.
    gemm_k<128, 128, 4, false><<<dim3(104, 6), dim3(256), 0, stream>>>(
        qc, kc, vc, pe,
        Wt, Wt + (size_t)1 * EMB * EMB, Wt + (size_t)2 * EMB * EMB, Wt + (size_t)4 * EMB * EMB,
        bq, bk, bv, bpos,
        Qp, Kp, Vtg, Rb);

    attn_rpe<<<dim3(8, NH, NB), dim3(256), 0, stream>>>(Qp, Kp, Vtg, Rb, rwb, rrb, Cx);

    // output GEMM: 64x64 tiles -> 768 blocks = 3 blocks/CU (R12: beat 64x96's 2/CU).
    gemm_k<64, 64, 1, true><<<dim3(64, 12), dim3(256), 0, stream>>>(
        Cx, Cx, Cx, Cx,
        Wt + (size_t)3 * EMB * EMB, Wt + (size_t)3 * EMB * EMB,
        Wt + (size_t)3 * EMB * EMB, Wt + (size_t)3 * EMB * EMB,
        bo, bo, bo, bo,
        out, out, out, out);
}